// Round 1
// baseline (12806.627 us; speedup 1.0000x reference)
//
#include <hip/hip_runtime.h>
#include <hip/hip_bf16.h>
#include <math.h>

#define D 512
#define NNODES 10000
#define NEDGES 80000
#define LAYERS 5
#define EPS 1e-5f

// ---------------- GEMM: Y[R,512] = X1@W1 (+ X2@W2), optional double-leaky ----
// W are [512,512] row-major slices of the [1024,512] concat weight.
#define BM 128
#define BN 128
#define BKK 16

template<bool TWO, bool ACT>
__global__ __launch_bounds__(256) void gemm_k(
    const float* __restrict__ X1, const float* __restrict__ X2,
    const float* __restrict__ W1, const float* __restrict__ W2,
    float* __restrict__ Y, int R)
{
  __shared__ float As[BKK][BM];
  __shared__ float Bs[BKK][BN];
  const int bn0 = blockIdx.x * BN;
  const int bm0 = blockIdx.y * BM;
  const int tid = threadIdx.x;
  const int tx = tid & 15;   // 16 col groups of 8
  const int ty = tid >> 4;   // 16 row groups of 8
  const int KT = TWO ? 1024 : 512;
  float acc[8][8];
#pragma unroll
  for (int i = 0; i < 8; i++)
#pragma unroll
    for (int j = 0; j < 8; j++) acc[i][j] = 0.f;

  for (int kt = 0; kt < KT; kt += BKK) {
    // A tile: 128 rows x 16 k = 512 float4, 2 per thread
#pragma unroll
    for (int h = 0; h < 2; ++h) {
      int idx = tid + h * 256;
      int row = idx >> 2;
      int kq = (idx & 3) * 4;
      int kg = kt + kq;
      int r = bm0 + row;
      float4 v = make_float4(0.f, 0.f, 0.f, 0.f);
      if (r < R) {
        const float* s = (TWO && kg >= 512) ? (X2 + (size_t)r * 512 + (kg - 512))
                                            : (X1 + (size_t)r * 512 + kg);
        v = *(const float4*)s;
      }
      As[kq + 0][row] = v.x; As[kq + 1][row] = v.y;
      As[kq + 2][row] = v.z; As[kq + 3][row] = v.w;
    }
    // B tile: 16 k x 128 n = 512 float4, 2 per thread
#pragma unroll
    for (int h = 0; h < 2; ++h) {
      int idx = tid + h * 256;
      int k = idx >> 5;
      int nq = (idx & 31) * 4;
      int kg = kt + k;
      const float* s = (TWO && kg >= 512) ? (W2 + (size_t)(kg - 512) * 512 + bn0 + nq)
                                          : (W1 + (size_t)kg * 512 + bn0 + nq);
      float4 v = *(const float4*)s;
      *(float4*)&Bs[k][nq] = v;
    }
    __syncthreads();
#pragma unroll
    for (int kk = 0; kk < BKK; ++kk) {
      float4 a0 = *(const float4*)&As[kk][ty * 8];
      float4 a1 = *(const float4*)&As[kk][ty * 8 + 4];
      float4 b0 = *(const float4*)&Bs[kk][tx * 8];
      float4 b1 = *(const float4*)&Bs[kk][tx * 8 + 4];
      float av[8] = {a0.x, a0.y, a0.z, a0.w, a1.x, a1.y, a1.z, a1.w};
      float bv[8] = {b0.x, b0.y, b0.z, b0.w, b1.x, b1.y, b1.z, b1.w};
#pragma unroll
      for (int i = 0; i < 8; i++)
#pragma unroll
        for (int j = 0; j < 8; j++)
          acc[i][j] = fmaf(av[i], bv[j], acc[i][j]);
    }
    __syncthreads();
  }
#pragma unroll
  for (int i = 0; i < 8; i++) {
    int r = bm0 + ty * 8 + i;
    if (r < R) {
      float* y = Y + (size_t)r * 512 + bn0 + tx * 8;
      float v[8];
#pragma unroll
      for (int j = 0; j < 8; j++) {
        float x = acc[i][j];
        if (ACT) x = (x >= 0.f) ? x : 0.01f * x;  // leaky(leaky(x,.1),.1)
        v[j] = x;
      }
      *(float4*)(y + 0) = make_float4(v[0], v[1], v[2], v[3]);
      *(float4*)(y + 4) = make_float4(v[4], v[5], v[6], v[7]);
    }
  }
}

// ---------------- ordered-float keys for atomicMax --------------------------
__device__ inline unsigned fkey(float f) {
  unsigned b = __float_as_uint(f);
  return (b & 0x80000000u) ? ~b : (b | 0x80000000u);
}
__device__ inline float funkey(unsigned k) {
  unsigned b = (k & 0x80000000u) ? (k ^ 0x80000000u) : ~k;
  return __uint_as_float(b);
}

// column maxes of sp = Ea + Na[dst], sr = Ea + Na[src]
__global__ __launch_bounds__(256) void colmax_k(
    const float* __restrict__ Ea, const float* __restrict__ Na,
    const int* __restrict__ src, const int* __restrict__ dst,
    unsigned* __restrict__ mp, unsigned* __restrict__ mr)
{
  const int t = threadIdx.x;
  float p0 = -1e30f, p1 = -1e30f, r0 = -1e30f, r1 = -1e30f;
  for (int e = blockIdx.x; e < NEDGES; e += gridDim.x) {
    int d = dst[e], s = src[e];
    const float* ea = Ea + (size_t)e * D;
    const float* nd = Na + (size_t)d * D;
    const float* ns = Na + (size_t)s * D;
    float e0 = ea[t], e1 = ea[t + 256];
    p0 = fmaxf(p0, e0 + nd[t]);       p1 = fmaxf(p1, e1 + nd[t + 256]);
    r0 = fmaxf(r0, e0 + ns[t]);       r1 = fmaxf(r1, e1 + ns[t + 256]);
  }
  atomicMax(&mp[t], fkey(p0));  atomicMax(&mp[t + 256], fkey(p1));
  atomicMax(&mr[t], fkey(r0));  atomicMax(&mr[t + 256], fkey(r1));
}

// z[dst] += exp(sp - mp)
__global__ __launch_bounds__(256) void zacc_k(
    const float* __restrict__ Ea, const float* __restrict__ Na,
    const int* __restrict__ dst, const unsigned* __restrict__ mp,
    float* __restrict__ z)
{
  __shared__ float smp[D];
  const int t = threadIdx.x;
  smp[t] = funkey(mp[t]); smp[t + 256] = funkey(mp[t + 256]);
  __syncthreads();
  for (int e = blockIdx.x; e < NEDGES; e += gridDim.x) {
    int d = dst[e];
    const float* ea = Ea + (size_t)e * D;
    const float* nd = Na + (size_t)d * D;
#pragma unroll
    for (int h = 0; h < 2; ++h) {
      int c = t + h * 256;
      float ap = __expf(ea[c] + nd[c] - smp[c]);
      atomicAdd(&z[(size_t)d * D + c], ap);
    }
  }
}

// z2[dst] += (ap/(z[dst]+eps)) * ex
__global__ __launch_bounds__(256) void z2acc_k(
    const float* __restrict__ Ea, const float* __restrict__ Na,
    const int* __restrict__ dst, const unsigned* __restrict__ mp,
    const float* __restrict__ z, const float* __restrict__ ex,
    float* __restrict__ z2)
{
  __shared__ float smp[D];
  const int t = threadIdx.x;
  smp[t] = funkey(mp[t]); smp[t + 256] = funkey(mp[t + 256]);
  __syncthreads();
  for (int e = blockIdx.x; e < NEDGES; e += gridDim.x) {
    int d = dst[e];
    const float* ea = Ea + (size_t)e * D;
    const float* nd = Na + (size_t)d * D;
    const float* xr = ex + (size_t)e * D;
#pragma unroll
    for (int h = 0; h < 2; ++h) {
      int c = t + h * 256;
      float ap = __expf(ea[c] + nd[c] - smp[c]);
      float a = ap / (z[(size_t)d * D + c] + EPS);
      atomicAdd(&z2[(size_t)d * D + c], a * xr[c]);
    }
  }
}

// blend (in-place over Ea): wr*nx[src] + wp*nx[dst], wr = sigmoid(lr - lp)
__global__ __launch_bounds__(256) void blend_k(
    float* __restrict__ Ea, const float* __restrict__ Na,
    const float* __restrict__ nx,
    const int* __restrict__ src, const int* __restrict__ dst,
    const unsigned* __restrict__ mp, const unsigned* __restrict__ mr)
{
  __shared__ float smp[D], smr[D];
  const int t = threadIdx.x;
  smp[t] = funkey(mp[t]); smp[t + 256] = funkey(mp[t + 256]);
  smr[t] = funkey(mr[t]); smr[t + 256] = funkey(mr[t + 256]);
  __syncthreads();
  for (int e = blockIdx.x; e < NEDGES; e += gridDim.x) {
    int d = dst[e], s = src[e];
    float* ea = Ea + (size_t)e * D;
    const float* nd = Na + (size_t)d * D;
    const float* ns = Na + (size_t)s * D;
    const float* xd = nx + (size_t)d * D;
    const float* xs = nx + (size_t)s * D;
#pragma unroll
    for (int h = 0; h < 2; ++h) {
      int c = t + h * 256;
      float eav = ea[c];
      float lp = eav + nd[c] - smp[c];
      float lr = eav + ns[c] - smr[c];
      float u = lr - lp;
      float wr;
      if (u >= 0.f) { float ev = __expf(-u); wr = 1.f / (1.f + ev); }
      else          { float ev = __expf(u);  wr = ev / (1.f + ev); }
      ea[c] = wr * xs[c] + (1.f - wr) * xd[c];
    }
  }
}

// node_conf = nx @ Wnc  ([512,55])
__global__ __launch_bounds__(256) void nodeconf_k(
    const float* __restrict__ nx, const float* __restrict__ Wnc,
    float* __restrict__ out)
{
  int w = threadIdx.x >> 6, lane = threadIdx.x & 63;
  int n = blockIdx.x * 4 + w;
  const float* r = nx + (size_t)n * D;
  if (lane < 55) {
    float acc = 0.f;
    for (int k = 0; k < D; k++) acc = fmaf(r[k], Wnc[k * 55 + lane], acc);
    out[(size_t)n * 55 + lane] = acc;
  }
}

// edge_conf = ex @ Wec  ([512,2])
__global__ __launch_bounds__(256) void edgeconf_k(
    const float* __restrict__ ex, const float* __restrict__ Wec,
    float* __restrict__ out)
{
  int w = threadIdx.x >> 6, lane = threadIdx.x & 63;
  int e = blockIdx.x * 4 + w;
  const float* r = ex + (size_t)e * D;
  float a0 = 0.f, a1 = 0.f;
#pragma unroll
  for (int j = 0; j < 8; j++) {
    int c = lane + j * 64;
    float x = r[c];
    a0 = fmaf(x, Wec[c * 2 + 0], a0);
    a1 = fmaf(x, Wec[c * 2 + 1], a1);
  }
#pragma unroll
  for (int off = 32; off; off >>= 1) {
    a0 += __shfl_down(a0, off);
    a1 += __shfl_down(a1, off);
  }
  if (lane == 0) { out[(size_t)e * 2 + 0] = a0; out[(size_t)e * 2 + 1] = a1; }
}

extern "C" void kernel_launch(void* const* d_in, const int* in_sizes, int n_in,
                              void* d_out, int out_size, void* d_ws, size_t ws_size,
                              hipStream_t stream)
{
  const float* in_nx = (const float*)d_in[0];
  const float* in_ex = (const float*)d_in[1];
  const int* src = (const int*)d_in[2];
  const int* dst = (const int*)d_in[3];
  const float* Wa = (const float*)d_in[4];
  const float* Wn = (const float*)d_in[5];
  const float* We = (const float*)d_in[6];
  const float* Wnc = (const float*)d_in[7];
  const float* Wec = (const float*)d_in[8];

  float* out = (float*)d_out;
  float* o_nx = out;
  float* o_nc = o_nx + (size_t)NNODES * D;
  float* o_ex = o_nc + (size_t)NNODES * 55;
  float* o_ec = o_ex + (size_t)NEDGES * D;

  float* ws = (float*)d_ws;
  float* ws_ex = ws;
  float* ws_nx = ws_ex + (size_t)NEDGES * D;
  float* Ea = ws_nx + (size_t)NNODES * D;
  float* Na = Ea + (size_t)NEDGES * D;
  float* z  = Na + (size_t)NNODES * D;
  float* z2 = z + (size_t)NNODES * D;
  unsigned* mp = (unsigned*)(z2 + (size_t)NNODES * D);
  // mr = mp + D (contiguous, covered by the same memset)

  dim3 gE(D / BN, NEDGES / BM);                 // (4, 625)
  dim3 gN(D / BN, (NNODES + BM - 1) / BM);      // (4, 79)
  const int EB = 2048;

  const float* nxCur = in_nx;
  const float* exCur = in_ex;
  for (int l = 0; l < LAYERS; l++) {
    float* nxNxt = (l & 1) ? ws_nx : o_nx;
    float* exNxt = (l & 1) ? ws_ex : o_ex;
    const float* Wal = Wa + (size_t)l * 1024 * 512;
    const float* Wnl = Wn + (size_t)l * 1024 * 512;
    const float* Wel = We + (size_t)l * 1024 * 512;
    unsigned* mr = mp + D;

    // zero z, z2, mp, mr (contiguous)
    hipMemsetAsync(z, 0, (size_t)NNODES * D * 2 * sizeof(float) + 2 * D * sizeof(unsigned), stream);

    // Ea = ex @ Wa_top ; Na = nx @ Wa_bot
    gemm_k<false, false><<<gE, 256, 0, stream>>>(exCur, nullptr, Wal, nullptr, Ea, NEDGES);
    gemm_k<false, false><<<gN, 256, 0, stream>>>(nxCur, nullptr, Wal + 512 * 512, nullptr, Na, NNODES);

    colmax_k<<<EB, 256, 0, stream>>>(Ea, Na, src, dst, mp, mr);
    zacc_k<<<EB, 256, 0, stream>>>(Ea, Na, dst, mp, z);
    z2acc_k<<<EB, 256, 0, stream>>>(Ea, Na, dst, mp, z, exCur, z2);

    // node update: nx' = act(z2@Wn_top + nx@Wn_bot)
    gemm_k<true, true><<<gN, 256, 0, stream>>>(z2, nxCur, Wnl, Wnl + 512 * 512, nxNxt, NNODES);

    // blend into Ea (in place), then edge update: ex' = act(blend@We_top + ex@We_bot)
    blend_k<<<EB, 256, 0, stream>>>(Ea, Na, nxCur, src, dst, mp, mr);
    gemm_k<true, true><<<gE, 256, 0, stream>>>(Ea, exCur, Wel, Wel + 512 * 512, exNxt, NEDGES);

    nxCur = nxNxt; exCur = exNxt;
  }

  nodeconf_k<<<NNODES / 4, 256, 0, stream>>>(nxCur, Wnc, o_nc);
  edgeconf_k<<<NEDGES / 4, 256, 0, stream>>>(exCur, Wec, o_ec);
}